// Round 1
// baseline (994.768 us; speedup 1.0000x reference)
//
#include <hip/hip_runtime.h>

// NCN fused: 4 modules, wave-per-chain (b,h,c), in-place y-sequence through d_out.
// x: [8,4096,1024] f32, xa: [8,8,1024] f32, W: [4,16,64,64] f32.
// out = concat(final x [8,4096,1024], final xa [8,8,1024]).

constexpr int B  = 8;
constexpr int T  = 4096;
constexpr int D  = 1024;
constexpr int H  = 16;
constexpr int DH = 64;
constexpr int NC = 8;
constexpr int NM = 4;
constexpr int STEPS = T / NC;  // 512

__global__ __launch_bounds__(256, 1)
void ncn_fused(const float* __restrict__ x, const float* __restrict__ xa,
               const float* __restrict__ w, float* __restrict__ out) {
  __shared__ alignas(16) float bc[4][DH];

  const int lane = threadIdx.x & 63;
  const int wv   = threadIdx.x >> 6;
  const int ch   = blockIdx.x * 4 + wv;   // chain id 0..1023
  const int c    = ch & (NC - 1);         // cache slot
  const int bh   = ch >> 3;
  const int h    = bh & (H - 1);
  const int b    = bh >> 4;

  float*       outx  = out;                         // [B,T,D]
  float*       outya = out + (size_t)B * T * D;     // [B,NC,D]

  // element address for this lane at time t: base + t*D
  const size_t base = (size_t)b * T * D + (size_t)h * DH + lane;

  // cache carry: module 0 inits from xa; modules 1..3 init from previous
  // module's final y (stays in this register).
  float y = xa[((size_t)b * NC + c) * D + (size_t)h * DH + lane];

  for (int m = 0; m < NM; ++m) {
    // W column for this lane: wreg[d] = W[m][h][d][lane]  (64 VGPRs, const-indexed)
    float wreg[DH];
    const float* wp = w + (size_t)(m * H + h) * DH * DH + lane;
#pragma unroll
    for (int d = 0; d < DH; ++d) wreg[d] = wp[(size_t)d * DH];

    const float* inp = (m == 0) ? x : outx;  // in-place after module 0

    // Module boundary: all our previous-module stores must be complete before
    // we load them back (same wave, same addresses).
    asm volatile("s_waitcnt vmcnt(0)" ::: "memory");

    int t = c;
    float vin = inp[base + (size_t)t * D];

    for (int i = 0; i < STEPS; ++i) {
      // stage input vector for broadcast
      bc[wv][lane] = vin;

      // prefetch next step's input (clamped uniform select, no branch)
      const int tn = (i + 1 < STEPS) ? (t + NC) : t;
      const float vnext = inp[base + (size_t)tn * D];

      asm volatile("s_waitcnt lgkmcnt(0)" ::: "memory");

      // mix[lane] = sum_d in[d] * W[d][lane]; uniform-addr b128 broadcasts
      float a0 = 0.f, a1 = 0.f, a2 = 0.f, a3 = 0.f;
      const float4* bq = (const float4*)(&bc[wv][0]);
#pragma unroll
      for (int j = 0; j < DH / 4; ++j) {
        const float4 q = bq[j];
        a0 = fmaf(q.x, wreg[4 * j + 0], a0);
        a1 = fmaf(q.y, wreg[4 * j + 1], a1);
        a2 = fmaf(q.z, wreg[4 * j + 2], a2);
        a3 = fmaf(q.w, wreg[4 * j + 3], a3);
      }
      const float mix = (a0 + a1) + (a2 + a3);

      // y = tanh(0.5*y + 0.5*mix) = tanh(z/2) = 1 - 2/(e^z + 1), z = y + mix
      const float z  = y + mix;
      const float ex = __expf(z);                       // inf/0 saturate correctly
      y = 1.0f - 2.0f * __builtin_amdgcn_rcpf(ex + 1.0f);

      outx[base + (size_t)t * D] = y;

      vin = vnext;
      t += NC;
    }
  }

  // final cache of last module -> ya
  outya[((size_t)b * NC + c) * D + (size_t)h * DH + lane] = y;
}

extern "C" void kernel_launch(void* const* d_in, const int* in_sizes, int n_in,
                              void* d_out, int out_size, void* d_ws, size_t ws_size,
                              hipStream_t stream) {
  (void)in_sizes; (void)n_in; (void)d_ws; (void)ws_size; (void)out_size;
  const float* x  = (const float*)d_in[0];
  const float* xa = (const float*)d_in[1];
  const float* w  = (const float*)d_in[2];
  float* out = (float*)d_out;

  dim3 grid(256), block(256);
  hipLaunchKernelGGL(ncn_fused, grid, block, 0, stream, x, xa, w, out);
}